// Round 7
// baseline (1624.337 us; speedup 1.0000x reference)
//
#include <hip/hip_runtime.h>
#include <hip/hip_bf16.h>
#include <cstddef>

// Problem constants (from reference)
#define BATCH 2
#define SEQ 4096
#define CMODEL 512
#define NHEADS 8
#define DHEAD 64
#define NTOK (BATCH * SEQ)          // 8192
#define SCALE 0.125f                // 1/sqrt(64)

typedef short  bf16x8 __attribute__((ext_vector_type(8)));
typedef float  f32x4  __attribute__((ext_vector_type(4)));
typedef unsigned short u16x8 __attribute__((ext_vector_type(8)));

__device__ __forceinline__ unsigned short bf16_rne(float f) {
    unsigned u = __float_as_uint(f);
    return (unsigned short)((u + 0x7fff + ((u >> 16) & 1)) >> 16);
}

// ---------------------------------------------------------------------------
// fp32 -> split bf16 (hi + residual lo), RNE both stages. n8 = elems / 8.
//   hi = bf16(x); lo = bf16(x - float(hi))
// ---------------------------------------------------------------------------
__global__ __launch_bounds__(256) void cvt_f32_bf16_split(
    const float* __restrict__ in,
    unsigned short* __restrict__ hi, unsigned short* __restrict__ lo, int n8)
{
    int i = blockIdx.x * blockDim.x + threadIdx.x;
    const int stride = gridDim.x * blockDim.x;
    for (; i < n8; i += stride) {
        float4 v0 = reinterpret_cast<const float4*>(in)[2 * i + 0];
        float4 v1 = reinterpret_cast<const float4*>(in)[2 * i + 1];
        float f[8] = {v0.x, v0.y, v0.z, v0.w, v1.x, v1.y, v1.z, v1.w};
        u16x8 rh, rl;
        #pragma unroll
        for (int j = 0; j < 8; ++j) {
            unsigned short h = bf16_rne(f[j]);
            rh[j] = h;
            float res = f[j] - __uint_as_float((unsigned)h << 16);
            rl[j] = bf16_rne(res);
        }
        *reinterpret_cast<u16x8*>(&hi[(size_t)i * 8]) = rh;
        *reinterpret_cast<u16x8*>(&lo[(size_t)i * 8]) = rl;
    }
}

// ---------------------------------------------------------------------------
// Split-bf16 MFMA GEMM: out = A @ W^T + bias, fp32-grade accuracy.
//   A ~ Ah+Al (M x K), W ~ Wh+Wl (N x K), all bf16 row-major; out fp32.
//   Per product: ah*bh + ah*bl + al*bh (drop lo*lo ~ 2^-18 rel).
//   mode 0: out row-major M x N
//   mode 1: out in (B, H, T, Dh) layout: m=(b,t), n=(h,d)
// Block: 64x64 tile, 256 thr = 4 waves; wave (w>>1, w&1) owns a 32x32
// quadrant = 2x2 tiles of mfma_f32_16x16x32_bf16. Fragments load straight
// from global (bf16x8 per lane); W hi+lo (1MB) is L2-resident, A L3-resident.
// Same-m-tile blocks (n=0..7) are 128 apart in dispatch order = same XCD
// (128 % 8 == 0), so the A-tile is read once into that XCD's L2 and reused.
// A-frag: row = lane&15, k = 8*(lane>>4)+j (contiguous in K). B-operand same
// pattern on W rows (computing A.W^T). C/D: col=lane&15, row=(lane>>4)*4+reg
// [verified mapping, learn_hip m89].
// ---------------------------------------------------------------------------
__global__ __launch_bounds__(256) void gemm_bf16s_mfma(
    const unsigned short* __restrict__ Ah, const unsigned short* __restrict__ Al,
    const unsigned short* __restrict__ Wh, const unsigned short* __restrict__ Wl,
    const float* __restrict__ bias, float* __restrict__ out,
    int M, int N, int K, int mode)
{
    const int tid  = threadIdx.x;
    const int lane = tid & 63;
    const int w    = tid >> 6;
    const int m0   = blockIdx.x * 64 + (w >> 1) * 32;
    const int n0   = blockIdx.y * 64 + (w & 1) * 32;
    const int row  = lane & 15;
    const int kg   = lane >> 4;          // 0..3

    f32x4 acc[2][2] = {};

    const size_t aoff0 = (size_t)(m0 + row)      * K + 8 * kg;
    const size_t aoff1 = (size_t)(m0 + 16 + row) * K + 8 * kg;
    const size_t woff0 = (size_t)(n0 + row)      * K + 8 * kg;
    const size_t woff1 = (size_t)(n0 + 16 + row) * K + 8 * kg;

    for (int k0 = 0; k0 < K; k0 += 32) {
        bf16x8 a0h = *reinterpret_cast<const bf16x8*>(Ah + aoff0 + k0);
        bf16x8 a1h = *reinterpret_cast<const bf16x8*>(Ah + aoff1 + k0);
        bf16x8 b0h = *reinterpret_cast<const bf16x8*>(Wh + woff0 + k0);
        bf16x8 b1h = *reinterpret_cast<const bf16x8*>(Wh + woff1 + k0);
        bf16x8 a0l = *reinterpret_cast<const bf16x8*>(Al + aoff0 + k0);
        bf16x8 a1l = *reinterpret_cast<const bf16x8*>(Al + aoff1 + k0);
        bf16x8 b0l = *reinterpret_cast<const bf16x8*>(Wl + woff0 + k0);
        bf16x8 b1l = *reinterpret_cast<const bf16x8*>(Wl + woff1 + k0);

        // hi*hi
        acc[0][0] = __builtin_amdgcn_mfma_f32_16x16x32_bf16(a0h, b0h, acc[0][0], 0, 0, 0);
        acc[0][1] = __builtin_amdgcn_mfma_f32_16x16x32_bf16(a0h, b1h, acc[0][1], 0, 0, 0);
        acc[1][0] = __builtin_amdgcn_mfma_f32_16x16x32_bf16(a1h, b0h, acc[1][0], 0, 0, 0);
        acc[1][1] = __builtin_amdgcn_mfma_f32_16x16x32_bf16(a1h, b1h, acc[1][1], 0, 0, 0);
        // hi*lo
        acc[0][0] = __builtin_amdgcn_mfma_f32_16x16x32_bf16(a0h, b0l, acc[0][0], 0, 0, 0);
        acc[0][1] = __builtin_amdgcn_mfma_f32_16x16x32_bf16(a0h, b1l, acc[0][1], 0, 0, 0);
        acc[1][0] = __builtin_amdgcn_mfma_f32_16x16x32_bf16(a1h, b0l, acc[1][0], 0, 0, 0);
        acc[1][1] = __builtin_amdgcn_mfma_f32_16x16x32_bf16(a1h, b1l, acc[1][1], 0, 0, 0);
        // lo*hi
        acc[0][0] = __builtin_amdgcn_mfma_f32_16x16x32_bf16(a0l, b0h, acc[0][0], 0, 0, 0);
        acc[0][1] = __builtin_amdgcn_mfma_f32_16x16x32_bf16(a0l, b1h, acc[0][1], 0, 0, 0);
        acc[1][0] = __builtin_amdgcn_mfma_f32_16x16x32_bf16(a1l, b0h, acc[1][0], 0, 0, 0);
        acc[1][1] = __builtin_amdgcn_mfma_f32_16x16x32_bf16(a1l, b1h, acc[1][1], 0, 0, 0);
    }

    #pragma unroll
    for (int i = 0; i < 2; ++i) {
        #pragma unroll
        for (int j = 0; j < 2; ++j) {
            const int c  = n0 + 16 * j + (lane & 15);
            const int rb = m0 + 16 * i + (lane >> 4) * 4;
            const float bv = bias[c];
            #pragma unroll
            for (int r = 0; r < 4; ++r) {
                const float v = acc[i][j][r] + bv;
                const int m = rb + r;
                if (mode == 0) {
                    out[(size_t)m * N + c] = v;
                } else {
                    const int b = m >> 12;          // / SEQ
                    const int t = m & (SEQ - 1);
                    const int h = c >> 6;           // / DHEAD
                    const int d = c & (DHEAD - 1);
                    out[((size_t)(b * NHEADS + h) * SEQ + t) * DHEAD + d] = v;
                }
            }
        }
    }
}

// ---------------------------------------------------------------------------
// Causal flash attention, fp32, split-K across 4 waves per block.
// Flat 1024-block grid, XCD-swizzled: dispatch index i -> xcd = i&7 (HW
// round-robins consecutive blocks across the 8 XCDs), slot = i>>3,
// bh = xcd + 8*(slot>>6), qt = slot&63.  All 64 q-tiles of one (b,h) land
// on ONE XCD (64 blocks = 2/CU x 32 CU), so that head's K+V (4MB fp32)
// fits the XCD's 4MB L2 instead of 8 heads thrashing it (T1 mechanism).
// Bijection check: i = (bh&7) + 8*(qt + 64*(bh>>3)).
//
// Block = 256 threads = 4 waves. Wave w owns a PRIVATE 16KB LDS region and
// processes key-subtiles ck = w, w+4, ... (KT=32 keys each) with online
// softmax into per-lane registers (lane owns query q = qt*64 + lane).
// No __syncthreads in the main loop (wave-private LDS => intra-wave
// ordering only). At the end, one barrier + 256-thread merge of the 4
// partials. Causal masking via predicate (p=0) — no exp(-inf - -inf) NaN.
// Epilogue FUSES fp32->split-bf16: writes hi/lo bf16 of the normalized
// output directly in (B, T, C) layout (feeds the Wo projection).
// ---------------------------------------------------------------------------
#define KT 32   // keys per sub-tile

__global__ __launch_bounds__(256) void attn_fwd(
    const float* __restrict__ Q, const float* __restrict__ K,
    const float* __restrict__ V,
    unsigned short* __restrict__ OutH, unsigned short* __restrict__ OutL)
{
    __shared__ float stage[4][2][KT][DHEAD];   // 64KB; reused for acc publish
    __shared__ float Msh[4][64];
    __shared__ float Lsh[4][64];

    const int tid  = threadIdx.x;
    const int lane = tid & 63;
    const int w    = tid >> 6;

    const int i    = blockIdx.x;        // 0..1023, XCD swizzle (see header)
    const int xcd  = i & 7;
    const int slot = i >> 3;            // 0..127
    const int bh   = xcd + 8 * (slot >> 6);
    const int qt   = slot & 63;

    const int b    = bh >> 3;
    const int h    = bh & 7;
    const int q    = qt * 64 + lane;

    const float* qptr = Q + ((size_t)bh * SEQ + q) * DHEAD;
    float qreg[DHEAD];
    #pragma unroll
    for (int i2 = 0; i2 < 16; ++i2) {
        float4 v = reinterpret_cast<const float4*>(qptr)[i2];
        qreg[4 * i2 + 0] = v.x; qreg[4 * i2 + 1] = v.y;
        qreg[4 * i2 + 2] = v.z; qreg[4 * i2 + 3] = v.w;
    }

    float acc[DHEAD] = {};
    float mrun = -INFINITY;
    float lrun = 0.f;

    float* ksh = &stage[w][0][0][0];
    float* vsh = &stage[w][1][0][0];

    const int ntiles = 2 * (qt + 1);
    for (int ck = w; ck < ntiles; ck += 4) {
        const int k0 = ck * KT;
        const float* kbase = K + ((size_t)bh * SEQ + k0) * DHEAD;
        const float* vbase = V + ((size_t)bh * SEQ + k0) * DHEAD;
        #pragma unroll
        for (int t = 0; t < 8; ++t) {
            const int f = lane * 4 + t * 256;
            *reinterpret_cast<float4*>(&ksh[f]) =
                *reinterpret_cast<const float4*>(&kbase[f]);
            *reinterpret_cast<float4*>(&vsh[f]) =
                *reinterpret_cast<const float4*>(&vbase[f]);
        }

        #pragma unroll 2
        for (int j = 0; j < KT; ++j) {
            const float4* krow = reinterpret_cast<const float4*>(&ksh[j * DHEAD]);
            float s0 = 0.f, s1 = 0.f, s2 = 0.f, s3 = 0.f;
            #pragma unroll
            for (int t = 0; t < 4; ++t) {
                float4 k0v = krow[4 * t + 0];
                float4 k1v = krow[4 * t + 1];
                float4 k2v = krow[4 * t + 2];
                float4 k3v = krow[4 * t + 3];
                s0 += qreg[16*t+ 0]*k0v.x + qreg[16*t+ 1]*k0v.y + qreg[16*t+ 2]*k0v.z + qreg[16*t+ 3]*k0v.w;
                s1 += qreg[16*t+ 4]*k1v.x + qreg[16*t+ 5]*k1v.y + qreg[16*t+ 6]*k1v.z + qreg[16*t+ 7]*k1v.w;
                s2 += qreg[16*t+ 8]*k2v.x + qreg[16*t+ 9]*k2v.y + qreg[16*t+10]*k2v.z + qreg[16*t+11]*k2v.w;
                s3 += qreg[16*t+12]*k3v.x + qreg[16*t+13]*k3v.y + qreg[16*t+14]*k3v.z + qreg[16*t+15]*k3v.w;
            }
            float s = ((s0 + s1) + (s2 + s3)) * SCALE;
            const bool valid = (k0 + j) <= q;
            if (valid && s > mrun) {
                float c = __expf(mrun - s);
                lrun *= c;
                #pragma unroll
                for (int d = 0; d < DHEAD; ++d) acc[d] *= c;
                mrun = s;
            }
            float p = valid ? __expf(s - mrun) : 0.f;
            lrun += p;
            const float4* vrow = reinterpret_cast<const float4*>(&vsh[j * DHEAD]);
            #pragma unroll
            for (int t = 0; t < 16; ++t) {
                float4 vv = vrow[t];
                acc[4 * t + 0] += p * vv.x; acc[4 * t + 1] += p * vv.y;
                acc[4 * t + 2] += p * vv.z; acc[4 * t + 3] += p * vv.w;
            }
        }
    }

    Msh[w][lane] = mrun;
    Lsh[w][lane] = lrun;
    float* awr = &stage[w][0][0][0];
    #pragma unroll
    for (int d = 0; d < DHEAD; d += 4) {
        const int c = (d + lane * 4) & 63;      // rotation swizzle
        float4 v;
        v.x = acc[d + 0]; v.y = acc[d + 1]; v.z = acc[d + 2]; v.w = acc[d + 3];
        *reinterpret_cast<float4*>(&awr[lane * DHEAD + c]) = v;
    }
    __syncthreads();

    {
        const int mq   = tid >> 2;       // query row 0..63
        const int dseg = tid & 3;        // 16-dim segment 0..3
        float m = Msh[0][mq];
        m = fmaxf(m, Msh[1][mq]);
        m = fmaxf(m, Msh[2][mq]);
        m = fmaxf(m, Msh[3][mq]);
        float lsum = 0.f;
        float o[16] = {};
        #pragma unroll
        for (int ww = 0; ww < 4; ++ww) {
            const float sc = __expf(Msh[ww][mq] - m);   // 0 for empty partials
            lsum += Lsh[ww][mq] * sc;
            const float* Aw = &stage[ww][0][0][0];
            #pragma unroll
            for (int t = 0; t < 16; ++t) {
                const int d = dseg * 16 + t;
                const int c = (d + mq * 4) & 63;
                o[t] += Aw[mq * DHEAD + c] * sc;
            }
        }
        const float inv = 1.f / lsum;
        // Fused split-bf16 write in (B, T, C) layout.
        const size_t base = ((size_t)(b * SEQ + qt * 64 + mq)) * CMODEL
                          + h * DHEAD + dseg * 16;
        u16x8 rh0, rh1, rl0, rl1;
        #pragma unroll
        for (int t = 0; t < 16; ++t) {
            const float vf = o[t] * inv;
            const unsigned short hh = bf16_rne(vf);
            const float res = vf - __uint_as_float((unsigned)hh << 16);
            const unsigned short ll = bf16_rne(res);
            if (t < 8) { rh0[t] = hh; rl0[t] = ll; }
            else       { rh1[t - 8] = hh; rl1[t - 8] = ll; }
        }
        *reinterpret_cast<u16x8*>(&OutH[base + 0]) = rh0;
        *reinterpret_cast<u16x8*>(&OutH[base + 8]) = rh1;
        *reinterpret_cast<u16x8*>(&OutL[base + 0]) = rl0;
        *reinterpret_cast<u16x8*>(&OutL[base + 8]) = rl1;
    }
}

// ---------------------------------------------------------------------------
extern "C" void kernel_launch(void* const* d_in, const int* in_sizes, int n_in,
                              void* d_out, int out_size, void* d_ws, size_t ws_size,
                              hipStream_t stream)
{
    const float* x  = (const float*)d_in[0];
    // d_in[1] = causal mask (tril) — deterministic, not needed.
    const float* Wq = (const float*)d_in[2];
    const float* bq = (const float*)d_in[3];
    const float* Wk = (const float*)d_in[4];
    const float* bk = (const float*)d_in[5];
    const float* Wv = (const float*)d_in[6];
    const float* bv = (const float*)d_in[7];
    const float* Wo = (const float*)d_in[8];
    const float* bo = (const float*)d_in[9];
    float* out = (float*)d_out;

    const size_t elems  = (size_t)BATCH * NHEADS * SEQ * DHEAD;  // 4,194,304
    const size_t welems = (size_t)CMODEL * CMODEL;               // 262,144

    // Workspace layout (~68 MB total):
    float* Qb = (float*)d_ws;                  // fp32 Q (B,H,T,Dh)
    float* Kb = Qb + elems;
    float* Vb = Kb + elems;
    unsigned short* p = (unsigned short*)(Vb + elems);
    unsigned short* xh  = p;  p += elems;      // bf16 hi/lo of x; REUSED as
    unsigned short* xl  = p;  p += elems;      // attn-output hi/lo (x dead then)
    unsigned short* Wqh = p;  p += welems;
    unsigned short* Wql = p;  p += welems;
    unsigned short* Wkh = p;  p += welems;
    unsigned short* Wkl = p;  p += welems;
    unsigned short* Wvh = p;  p += welems;
    unsigned short* Wvl = p;  p += welems;
    unsigned short* Woh = p;  p += welems;
    unsigned short* Wol = p;  p += welems;

    cvt_f32_bf16_split<<<2048, 256, 0, stream>>>(x,  xh,  xl,  (int)(elems  / 8));
    cvt_f32_bf16_split<<<128,  256, 0, stream>>>(Wq, Wqh, Wql, (int)(welems / 8));
    cvt_f32_bf16_split<<<128,  256, 0, stream>>>(Wk, Wkh, Wkl, (int)(welems / 8));
    cvt_f32_bf16_split<<<128,  256, 0, stream>>>(Wv, Wvh, Wvl, (int)(welems / 8));
    cvt_f32_bf16_split<<<128,  256, 0, stream>>>(Wo, Woh, Wol, (int)(welems / 8));

    dim3 gemm_grid(NTOK / 64, CMODEL / 64);   // (128, 8)
    gemm_bf16s_mfma<<<gemm_grid, 256, 0, stream>>>(xh, xl, Wqh, Wql, bq, Qb, NTOK, CMODEL, CMODEL, 1);
    gemm_bf16s_mfma<<<gemm_grid, 256, 0, stream>>>(xh, xl, Wkh, Wkl, bk, Kb, NTOK, CMODEL, CMODEL, 1);
    gemm_bf16s_mfma<<<gemm_grid, 256, 0, stream>>>(xh, xl, Wvh, Wvl, bv, Vb, NTOK, CMODEL, CMODEL, 1);

    // Attention: reads fp32 Q/K/V, writes split-bf16 output into xh/xl
    // (x's bf16 copies are dead once Q/K/V exist; stream order makes this safe).
    attn_fwd<<<dim3(SEQ / 64 * BATCH * NHEADS), 256, 0, stream>>>(Qb, Kb, Vb, xh, xl);

    gemm_bf16s_mfma<<<gemm_grid, 256, 0, stream>>>(xh, xl, Woh, Wol, bo, out, NTOK, CMODEL, CMODEL, 0);
}